// Round 18
// baseline (757.859 us; speedup 1.0000x reference)
//
#include <hip/hip_runtime.h>
#include <hip/hip_bf16.h>

// VQ-VAE forward, B=64, F=16.  ALL I/O float32 (d_out = float*: decoded 4194304 f32, indices 262144 f32).
// ws layout: f1 (64 MiB) | f2 (16 MiB) | f3 (16 MiB) = 96 MiB.
// R18: conv1 -> f1 fp32 CHANNEL-LAST (coalesced 64B/lane stores); conv2 reads it as 4x float4
//      per tap (64 vector loads/thread vs 256 scalar). Encoder math still exact fp32 (VQ indices
//      are sacred: split-bf16 would flip ~100 argmins). Decoder: tconv1 stores bf16 ch-last,
//      tconv2 stages from bf16 (both byte-halved; decoder-only precision, headroom 300x).
// Ledger (R17): conv2 62.7 | conv1 ~27 | res ~20x3 | res_bf16 ~20 | vq ~12 | tconv1_mfma ~12 | tconv2 ~35.
// Lessons: uniform weights -> SGPR (R10); scalar-conv issue capped ~20-30% on this toolchain ->
//      vectorize loads or use matrix pipe (R17); encoder precision untouchable (index flips).

#define R16X(M) M(0) M(1) M(2) M(3) M(4) M(5) M(6) M(7) M(8) M(9) M(10) M(11) M(12) M(13) M(14) M(15)
#define R8X(M)  M(0) M(1) M(2) M(3) M(4) M(5) M(6) M(7)

typedef __attribute__((ext_vector_type(8))) short          bf16x8;
typedef __attribute__((ext_vector_type(8))) unsigned short u16x8;
typedef __attribute__((ext_vector_type(4))) float          f32x4;

__device__ __forceinline__ unsigned short f2bf(float f) {   // RNE fp32 -> bf16 bits
    unsigned u; __builtin_memcpy(&u, &f, 4);
    unsigned r = u + 0x7FFFu + ((u >> 16) & 1u);
    return (unsigned short)(r >> 16);
}
__device__ __forceinline__ float bf2f(unsigned short h) {
    unsigned u = ((unsigned)h) << 16;
    float f; __builtin_memcpy(&f, &u, 4);
    return f;
}

// ---------------- conv1: 1->16, 256->128 — writes fp32 CHANNEL-LAST (64,128,128,16) ----------------
__global__ __launch_bounds__(256) void conv1_k(const float* __restrict__ x, const float* __restrict__ w,
                                               const float* __restrict__ bias, float* __restrict__ out) {
    int idx = blockIdx.x * 256 + threadIdx.x;   // 64*128*128
    int ox = idx & 127;
    int oy = (idx >> 7) & 127;
    int b  = idx >> 14;
    const float* xin = x + (size_t)b * 65536;
    float pv[16];
#pragma unroll
    for (int ky = 0; ky < 4; ++ky) {
        int iy = 2 * oy - 1 + ky;
#pragma unroll
        for (int kx = 0; kx < 4; ++kx) {
            int ix = 2 * ox - 1 + kx;
            pv[ky * 4 + kx] = (iy >= 0 && iy < 256 && ix >= 0 && ix < 256)
                                  ? xin[iy * 256 + ix] : 0.f;
        }
    }
    float4* o = (float4*)(out + (size_t)idx * 16);   // channel-last
#pragma unroll
    for (int j = 0; j < 4; ++j) {
        float4 t;
#pragma unroll
        for (int e = 0; e < 4; ++e) {
            int oc = j * 4 + e;
            float acc = bias[oc];
#pragma unroll
            for (int k = 0; k < 16; ++k) acc = fmaf(pv[k], w[oc * 16 + k], acc);
            ((float*)&t)[e] = fmaxf(acc, 0.f);
        }
        o[j] = t;
    }
}

// ---------------- conv2: 16->16, 128->64 — ch-last input, float4 taps, oc-halved ----------------
__global__ __launch_bounds__(256) void conv2_k(const float* __restrict__ in, const float* __restrict__ w,
                                               const float* __restrict__ bias, float* __restrict__ out) {
    int half = blockIdx.x >> 10;
    int idx  = (blockIdx.x & 1023) * 256 + threadIdx.x;   // 64*64*64
    int ox = idx & 63;
    int oy = (idx >> 6) & 63;
    int b  = idx >> 12;
    int ocb = half * 8;
    const float* xin = in + (size_t)b * 262144;   // (128,128,16) channel-last
    const float* wb  = w + ocb * 256;             // (oc,ic,4,4)
#define DECLA(i) float a##i = bias[ocb + i];
    R8X(DECLA)
#undef DECLA
    const float4 z4 = { 0.f, 0.f, 0.f, 0.f };
#pragma unroll
    for (int ky = 0; ky < 4; ++ky) {
        int jy = 2 * oy - 1 + ky;
        bool yok = (jy >= 0) && (jy < 128);
#pragma unroll
        for (int kx = 0; kx < 4; ++kx) {
            int jx = 2 * ox - 1 + kx;
            bool ok = yok && (jx >= 0) && (jx < 128);
            const float4* p4 = (const float4*)(xin + ((size_t)(jy * 128 + jx) << 4));
            float4 v0 = ok ? p4[0] : z4;
            float4 v1 = ok ? p4[1] : z4;
            float4 v2 = ok ? p4[2] : z4;
            float4 v3 = ok ? p4[3] : z4;
            const int tap = ky * 4 + kx;   // compile-time literal
#define FT(oc) { const float* q = wb + oc * 256 + tap; \
            a##oc = fmaf(v0.x, q[0],   a##oc); a##oc = fmaf(v0.y, q[16],  a##oc); \
            a##oc = fmaf(v0.z, q[32],  a##oc); a##oc = fmaf(v0.w, q[48],  a##oc); \
            a##oc = fmaf(v1.x, q[64],  a##oc); a##oc = fmaf(v1.y, q[80],  a##oc); \
            a##oc = fmaf(v1.z, q[96],  a##oc); a##oc = fmaf(v1.w, q[112], a##oc); \
            a##oc = fmaf(v2.x, q[128], a##oc); a##oc = fmaf(v2.y, q[144], a##oc); \
            a##oc = fmaf(v2.z, q[160], a##oc); a##oc = fmaf(v2.w, q[176], a##oc); \
            a##oc = fmaf(v3.x, q[192], a##oc); a##oc = fmaf(v3.y, q[208], a##oc); \
            a##oc = fmaf(v3.z, q[224], a##oc); a##oc = fmaf(v3.w, q[240], a##oc); }
            R8X(FT)
#undef FT
        }
    }
    float* o = out + (size_t)b * (16 * 4096) + (size_t)ocb * 4096 + oy * 64 + ox;   // NCHW
#define STO(oc) o[oc * 4096] = fmaxf(a##oc, 0.f);
    R8X(STO)
#undef STO
}

// ---------------- residual block — oc-split halves, 2048 blocks, 8 acc/thread (NCHW) ----------------
__global__ __launch_bounds__(256) void res_k(const float* __restrict__ in, const float* __restrict__ w,
                                             const float* __restrict__ bias, float* __restrict__ out) {
    int half = blockIdx.x >> 10;
    int idx  = (blockIdx.x & 1023) * 256 + threadIdx.x;   // 64*64*64
    int ox = idx & 63;
    int oy = (idx >> 6) & 63;
    int b  = idx >> 12;
    int ocb = half * 8;
    const float* xin = in + (size_t)b * 65536;
    const float* wb  = w + (size_t)ocb * 144;
#define DECLB(i) float a##i = bias[ocb + i];
    R8X(DECLB)
#undef DECLB
    bool yt = (oy > 0), yb = (oy < 63);
    bool xl = (ox > 0), xr = (ox < 63);
    for (int ic = 0; ic < 16; ++ic) {
        const float* xb = xin + ic * 4096 + (oy - 1) * 64 + (ox - 1);
        float pa0 = (yt && xl) ? xb[0]       : 0.f;
        float pa1 =  yt        ? xb[1]       : 0.f;
        float pa2 = (yt && xr) ? xb[2]       : 0.f;
        float pb0 =  xl        ? xb[64 + 0]  : 0.f;
        float pb1 =              xb[64 + 1];
        float pb2 =  xr        ? xb[64 + 2]  : 0.f;
        float pc0 = (yb && xl) ? xb[128 + 0] : 0.f;
        float pc1 =  yb        ? xb[128 + 1] : 0.f;
        float pc2 = (yb && xr) ? xb[128 + 2] : 0.f;
        const float* wp = wb + ic * 9;
#define FMAR(oc) { const float* q = wp + oc * 144; \
        a##oc = fmaf(pa0, q[0], a##oc); a##oc = fmaf(pa1, q[1], a##oc); a##oc = fmaf(pa2, q[2], a##oc); \
        a##oc = fmaf(pb0, q[3], a##oc); a##oc = fmaf(pb1, q[4], a##oc); a##oc = fmaf(pb2, q[5], a##oc); \
        a##oc = fmaf(pc0, q[6], a##oc); a##oc = fmaf(pc1, q[7], a##oc); a##oc = fmaf(pc2, q[8], a##oc); }
        R8X(FMAR)
#undef FMAR
    }
    float* o        = out + (size_t)b * 65536 + (size_t)ocb * 4096 + oy * 64 + ox;
    const float* rr = xin + (size_t)ocb * 4096 + oy * 64 + ox;
#define RSTO(oc) o[oc * 4096] = rr[oc * 4096] + fmaxf(a##oc, 0.f);
    R8X(RSTO)
#undef RSTO
}

// ---------------- res variant for dr2: writes bf16 CHANNEL-LAST (64,64,64,16) ----------------
__global__ __launch_bounds__(256) void res_bf16_k(const float* __restrict__ in, const float* __restrict__ w,
                                                  const float* __restrict__ bias, unsigned short* __restrict__ outb) {
    int half = blockIdx.x >> 10;
    int idx  = (blockIdx.x & 1023) * 256 + threadIdx.x;   // 64*64*64
    int ox = idx & 63;
    int oy = (idx >> 6) & 63;
    int b  = idx >> 12;
    int ocb = half * 8;
    const float* xin = in + (size_t)b * 65536;
    const float* wb  = w + (size_t)ocb * 144;
#define DECLB(i) float a##i = bias[ocb + i];
    R8X(DECLB)
#undef DECLB
    bool yt = (oy > 0), yb = (oy < 63);
    bool xl = (ox > 0), xr = (ox < 63);
    for (int ic = 0; ic < 16; ++ic) {
        const float* xb = xin + ic * 4096 + (oy - 1) * 64 + (ox - 1);
        float pa0 = (yt && xl) ? xb[0]       : 0.f;
        float pa1 =  yt        ? xb[1]       : 0.f;
        float pa2 = (yt && xr) ? xb[2]       : 0.f;
        float pb0 =  xl        ? xb[64 + 0]  : 0.f;
        float pb1 =              xb[64 + 1];
        float pb2 =  xr        ? xb[64 + 2]  : 0.f;
        float pc0 = (yb && xl) ? xb[128 + 0] : 0.f;
        float pc1 =  yb        ? xb[128 + 1] : 0.f;
        float pc2 = (yb && xr) ? xb[128 + 2] : 0.f;
        const float* wp = wb + ic * 9;
#define FMAR(oc) { const float* q = wp + oc * 144; \
        a##oc = fmaf(pa0, q[0], a##oc); a##oc = fmaf(pa1, q[1], a##oc); a##oc = fmaf(pa2, q[2], a##oc); \
        a##oc = fmaf(pb0, q[3], a##oc); a##oc = fmaf(pb1, q[4], a##oc); a##oc = fmaf(pb2, q[5], a##oc); \
        a##oc = fmaf(pc0, q[6], a##oc); a##oc = fmaf(pc1, q[7], a##oc); a##oc = fmaf(pc2, q[8], a##oc); }
        R8X(FMAR)
#undef FMAR
    }
    const float* rr = xin + (size_t)ocb * 4096 + oy * 64 + ox;
    u16x8 pk;
#define PK(oc) pk[oc] = f2bf(rr[oc * 4096] + fmaxf(a##oc, 0.f));
    R8X(PK)
#undef PK
    *(u16x8*)(outb + (((size_t)b * 4096) + oy * 64 + ox) * 16 + ocb) = pk;
}

// ---------------- VQ: rows of 16 contiguous floats (raw NCHW flatten), K=64 ----------------
__global__ __launch_bounds__(256) void vq_k(const float* __restrict__ h, const float* __restrict__ cb,
                                            float* __restrict__ q, float* __restrict__ idx_out) {
    __shared__ float cbs[1024];  // 64 x 16
    __shared__ float cn[64];
    for (int i = threadIdx.x; i < 1024; i += 256) cbs[i] = cb[i];
    __syncthreads();
    if (threadIdx.x < 64) {
        float s = 0.f;
#pragma unroll
        for (int d = 0; d < 16; ++d) { float v = cbs[threadIdx.x * 16 + d]; s = fmaf(v, v, s); }
        cn[threadIdx.x] = s;
    }
    __syncthreads();
    int r = blockIdx.x * 256 + threadIdx.x;   // 262144 rows
    float f[16];
    const float4* hp = (const float4*)(h + (size_t)r * 16);
#pragma unroll
    for (int j = 0; j < 4; ++j) {
        float4 v = hp[j];
        f[j * 4 + 0] = v.x; f[j * 4 + 1] = v.y; f[j * 4 + 2] = v.z; f[j * 4 + 3] = v.w;
    }
    float best = 3.4e38f;
    int bi = 0;
    for (int k = 0; k < 64; ++k) {
        float dot = 0.f;
#pragma unroll
        for (int d = 0; d < 16; ++d) dot = fmaf(f[d], cbs[k * 16 + d], dot);
        float dist = cn[k] - 2.f * dot;   // +||f||^2 is per-row constant, argmin-invariant
        if (dist < best) { best = dist; bi = k; }
    }
    float4* qp = (float4*)(q + (size_t)r * 16);
    const float4* cp = (const float4*)(cbs + bi * 16);
#pragma unroll
    for (int j = 0; j < 4; ++j) qp[j] = cp[j];
    idx_out[r] = (float)bi;
}

// ---------------- tconv1 via MFMA: per parity class GEMM M=262144 N=16 K=64 — bf16 out ----------------
// A[px][k] (k=tap*16+ic) from bf16 ch-last (64,64,64,16); B' = W'[k][oc]; C -> f1 ch-last BF16.
__global__ __launch_bounds__(256) void tconv1_mfma_k(const unsigned short* __restrict__ xb,
                                                     const float* __restrict__ w1, const float* __restrict__ bia,
                                                     unsigned short* __restrict__ outb) {
    int cls = blockIdx.x >> 9;           // 4 classes x 512 blocks
    int bb  = blockIdx.x & 511;
    int DY = cls >> 1, DX = cls & 1;
    int wid  = threadIdx.x >> 6;
    int lane = threadIdx.x & 63;
    int oc = lane & 15;                  // B col / C col; also A px-row index
    int kg = lane >> 4;                  // 0..3: k-group of 8

    bf16x8 bfr0, bfr1;
    float accb = bia[oc];
#pragma unroll
    for (int m = 0; m < 2; ++m) {
        int tap = 2 * m + (kg >> 1);
        int ty = tap >> 1, tx = tap & 1;
        int koff = (3 - DY - 2 * ty) * 4 + (3 - DX - 2 * tx);
        int ic0 = (kg & 1) * 8;
        bf16x8 t;
#pragma unroll
        for (int j = 0; j < 8; ++j)
            t[j] = (short)f2bf(w1[(ic0 + j) * 256 + oc * 16 + koff]);
        if (m == 0) bfr0 = t; else bfr1 = t;
    }

    int Wc = bb * 4 + wid;               // 0..2047 within class
    for (int t = 0; t < 8; ++t) {
        int tile = Wc * 8 + t;           // 0..16383
        int v0  = (tile & 3) * 16;
        int u   = (tile >> 2) & 63;
        int img = tile >> 8;
        const unsigned short* xi = xb + (size_t)img * 65536;   // 4096 px x 16 ch
        f32x4 acc = { accb, accb, accb, accb };
#pragma unroll
        for (int m = 0; m < 2; ++m) {
            int tap = 2 * m + (kg >> 1);
            int ty = tap >> 1, tx = tap & 1;
            int jy = u + DY - 1 + ty;
            int jx = v0 + oc + DX - 1 + tx;
            bf16x8 a = { 0, 0, 0, 0, 0, 0, 0, 0 };
            if (jy >= 0 && jy < 64 && jx >= 0 && jx < 64) {
                int ic0 = (kg & 1) * 8;
                a = *(const bf16x8*)(xi + ((jy * 64 + jx) * 16 + ic0));
            }
            acc = __builtin_amdgcn_mfma_f32_16x16x32_bf16(a, (m == 0 ? bfr0 : bfr1), acc, 0, 0, 0);
        }
        int my = 2 * u + DY;
#pragma unroll
        for (int r = 0; r < 4; ++r) {
            int pxr = kg * 4 + r;
            int mx  = 2 * (v0 + pxr) + DX;
            outb[(((size_t)img * 16384) + my * 128 + mx) * 16 + oc] = f2bf(fmaxf(acc[r], 0.f));
        }
    }
}

// ---------------- tconv2: ConvTranspose2d 16->1, k4 s2 p1, 128->256 — bf16 input ----------------
#define P2 20
__global__ __launch_bounds__(256) void tconv2_k(const unsigned short* __restrict__ f1b,
                                                const float* __restrict__ w2, const float* __restrict__ b2,
                                                float* __restrict__ out) {
    __shared__ float s1[324 * P2];       // [pixel(18x18)][16 ch + pad4]
    __shared__ float ws2[256];           // (ic,1,4,4)
    __shared__ float b2s;
    if (threadIdx.x < 256) ws2[threadIdx.x] = w2[threadIdx.x];
    if (threadIdx.x == 0) b2s = b2[0];

    int tile = blockIdx.x & 63;
    int b    = blockIdx.x >> 6;
    int Y0 = (tile >> 3) * 32;
    int X0 = (tile & 7) * 32;
    int m0 = (Y0 >> 1) - 1;
    int n0 = (X0 >> 1) - 1;
    const unsigned short* fb = f1b + (size_t)b * 262144;   // (128,128,16) ch-last bf16

    for (int i = threadIdx.x; i < 5184; i += 256) {
        int p  = i >> 4;
        int ic = i & 15;
        int my = m0 + p / 18;
        int mx = n0 + p % 18;
        float v = 0.f;
        if (my >= 0 && my < 128 && mx >= 0 && mx < 128)
            v = bf2f(fb[((size_t)(my * 128 + mx)) * 16 + ic]);
        s1[p * P2 + ic] = v;
    }
    __syncthreads();

    int ly0 = threadIdx.x >> 5;
    int lx  = threadIdx.x & 31;
    int gx  = X0 + lx;
    int kyb = (Y0 + ly0 + 1) & 1;
    int kxb = (gx + 1) & 1;
    float wr[2][2][16];
#pragma unroll
    for (int a = 0; a < 2; ++a) {
#pragma unroll
        for (int c = 0; c < 2; ++c) {
            int ky = kyb + 2 * a, kx = kxb + 2 * c;
#pragma unroll
            for (int ic = 0; ic < 16; ++ic)
                wr[a][c][ic] = ws2[ic * 16 + ky * 4 + kx];
        }
    }
    int sx[2];
#pragma unroll
    for (int c = 0; c < 2; ++c) sx[c] = ((gx + 1 - (kxb + 2 * c)) >> 1) - n0;

#pragma unroll
    for (int r = 0; r < 4; ++r) {
        int gy = Y0 + ly0 + 8 * r;
        float acc = b2s;
#pragma unroll
        for (int a = 0; a < 2; ++a) {
            int sy = ((gy + 1 - (kyb + 2 * a)) >> 1) - m0;
#pragma unroll
            for (int c = 0; c < 2; ++c) {
                const float4* sp4 = (const float4*)&s1[(sy * 18 + sx[c]) * P2];
#pragma unroll
                for (int j = 0; j < 4; ++j) {
                    float4 v = sp4[j];
                    acc = fmaf(v.x, wr[a][c][j * 4 + 0], acc);
                    acc = fmaf(v.y, wr[a][c][j * 4 + 1], acc);
                    acc = fmaf(v.z, wr[a][c][j * 4 + 2], acc);
                    acc = fmaf(v.w, wr[a][c][j * 4 + 3], acc);
                }
            }
        }
        out[(size_t)b * 65536 + gy * 256 + gx] = acc;
    }
}

extern "C" void kernel_launch(void* const* d_in, const int* in_sizes, int n_in,
                              void* d_out, int out_size, void* d_ws, size_t ws_size,
                              hipStream_t stream) {
    const float* x    = (const float*)d_in[0];
    const float* c1w  = (const float*)d_in[1];
    const float* c1b  = (const float*)d_in[2];
    const float* c2w  = (const float*)d_in[3];
    const float* c2b  = (const float*)d_in[4];
    const float* er1w = (const float*)d_in[5];
    const float* er1b = (const float*)d_in[6];
    const float* er2w = (const float*)d_in[7];
    const float* er2b = (const float*)d_in[8];
    const float* cb   = (const float*)d_in[9];
    const float* dr1w = (const float*)d_in[10];
    const float* dr1b = (const float*)d_in[11];
    const float* dr2w = (const float*)d_in[12];
    const float* dr2b = (const float*)d_in[13];
    const float* t1w  = (const float*)d_in[14];
    const float* t1b  = (const float*)d_in[15];
    const float* t2w  = (const float*)d_in[16];
    const float* t2b  = (const float*)d_in[17];

    float* f1 = (float*)d_ws;                                // 64 MiB: enc fp32 ch-last / dec bf16 ch-last
    float* f2 = (float*)((char*)d_ws + 67108864);            // (64,16,64,64)
    float* f3 = (float*)((char*)d_ws + 67108864 + 16777216); // (64,16,64,64) / bf16 ch-last (8.4 MiB)

    float* out     = (float*)d_out;                          // decoded: 4,194,304 f32
    float* idx_out = out + 4194304;                          // indices: 262,144 f32

    conv1_k     <<<4096, 256, 0, stream>>>(x, c1w, c1b, f1);
    conv2_k     <<<2048, 256, 0, stream>>>(f1, c2w, c2b, f2);
    res_k       <<<2048, 256, 0, stream>>>(f2, er1w, er1b, f3);  // er1
    res_k       <<<2048, 256, 0, stream>>>(f3, er2w, er2b, f2);  // er2
    vq_k        <<<1024, 256, 0, stream>>>(f2, cb, f3, idx_out); // quantized -> f3
    res_k       <<<2048, 256, 0, stream>>>(f3, dr1w, dr1b, f2);  // dr1
    res_bf16_k  <<<2048, 256, 0, stream>>>(f2, dr2w, dr2b, (unsigned short*)f3);  // dr2 -> bf16 ch-last
    tconv1_mfma_k<<<2048, 256, 0, stream>>>((const unsigned short*)f3, t1w, t1b, (unsigned short*)f1);
    tconv2_k    <<<4096, 256, 0, stream>>>((const unsigned short*)f1, t2w, t2b, out);
}

// Round 19
// 280.742 us; speedup vs baseline: 2.6995x; 2.6995x over previous
//
#include <hip/hip_runtime.h>
#include <hip/hip_bf16.h>

// VQ-VAE forward, B=64, F=16.  ALL I/O float32 (d_out = float*: decoded 4194304 f32, indices 262144 f32).
// ws layout: f1 (64 MiB) | f2 (16 MiB) | f3 (16 MiB) = 96 MiB.
// R19: conv1/conv2 reverted to R17 exact forms (R18's ch-last conv2: VGPR 156, occ 12%, 550us —
//      wide-vector full-unroll blows registers on this toolchain). NEW: tconv2 as per-pixel
//      4-parity-class kernel (conv1-shape: tiny state, literal weight idx -> SGPR, no LDS).
// Ledger (R17): conv2 62.7 | conv1 ~27 | res ~20x3 | res_bf16 ~20 | vq ~12 | tconv1_mfma ~12 | tconv2 ~35.
// Lessons: uniform weights -> SGPR (R10); matrix pipe for decoder convs (R17); small-state +
//      high-occupancy or bust (R11-R18); never full-unroll wide vector loads (R7, R18).

#define R16X(M) M(0) M(1) M(2) M(3) M(4) M(5) M(6) M(7) M(8) M(9) M(10) M(11) M(12) M(13) M(14) M(15)
#define R8X(M)  M(0) M(1) M(2) M(3) M(4) M(5) M(6) M(7)

typedef __attribute__((ext_vector_type(8))) short          bf16x8;
typedef __attribute__((ext_vector_type(8))) unsigned short u16x8;
typedef __attribute__((ext_vector_type(4))) float          f32x4;

__device__ __forceinline__ unsigned short f2bf(float f) {   // RNE fp32 -> bf16 bits
    unsigned u; __builtin_memcpy(&u, &f, 4);
    unsigned r = u + 0x7FFFu + ((u >> 16) & 1u);
    return (unsigned short)(r >> 16);
}
__device__ __forceinline__ float bf2f(unsigned short h) {
    unsigned u = ((unsigned)h) << 16;
    float f; __builtin_memcpy(&f, &u, 4);
    return f;
}

// ---------------- conv1: 1->16, 256->128 (R17 exact: NCHW out) ----------------
__global__ __launch_bounds__(256) void conv1_k(const float* __restrict__ x, const float* __restrict__ w,
                                               const float* __restrict__ bias, float* __restrict__ out) {
    int idx = blockIdx.x * 256 + threadIdx.x;   // 64*128*128
    int ox = idx & 127;
    int oy = (idx >> 7) & 127;
    int b  = idx >> 14;
    const float* xin = x + (size_t)b * 65536;
    float pv[16];
#pragma unroll
    for (int ky = 0; ky < 4; ++ky) {
        int iy = 2 * oy - 1 + ky;
#pragma unroll
        for (int kx = 0; kx < 4; ++kx) {
            int ix = 2 * ox - 1 + kx;
            pv[ky * 4 + kx] = (iy >= 0 && iy < 256 && ix >= 0 && ix < 256)
                                  ? xin[iy * 256 + ix] : 0.f;
        }
    }
    float* o = out + (size_t)b * (16 * 16384) + oy * 128 + ox;
#pragma unroll
    for (int oc = 0; oc < 16; ++oc) {
        float acc = bias[oc];
#pragma unroll
        for (int k = 0; k < 16; ++k) acc = fmaf(pv[k], w[oc * 16 + k], acc);
        o[oc * 16384] = fmaxf(acc, 0.f);
    }
}

// ---------------- conv2: 16->16, 128->64 — R17 exact (NCHW scalar, oc-halved) ----------------
__global__ __launch_bounds__(256) void conv2_k(const float* __restrict__ in, const float* __restrict__ w,
                                               const float* __restrict__ bias, float* __restrict__ out) {
    int half = blockIdx.x >> 10;
    int idx  = (blockIdx.x & 1023) * 256 + threadIdx.x;   // 64*64*64
    int ox = idx & 63;
    int oy = (idx >> 6) & 63;
    int b  = idx >> 12;
    int ocb = half * 8;
    const float* xin = in + (size_t)b * (16 * 16384);
    const float* wb  = w + ocb * 256;
#define DECLA(i) float a##i = bias[ocb + i];
    R8X(DECLA)
#undef DECLA
    int iy0 = 2 * oy - 1, ix0 = 2 * ox - 1;
    bool y0ok = (iy0 >= 0), y3ok = (iy0 + 3 < 128);
    bool x0ok = (ix0 >= 0), x3ok = (ix0 + 3 < 128);
    for (int ic = 0; ic < 16; ++ic) {
        const float* xc = xin + ic * 16384 + iy0 * 128 + ix0;
        float p0  = (y0ok && x0ok) ? xc[0]       : 0.f;
        float p1  =  y0ok          ? xc[1]       : 0.f;
        float p2  =  y0ok          ? xc[2]       : 0.f;
        float p3  = (y0ok && x3ok) ? xc[3]       : 0.f;
        float p4  =  x0ok          ? xc[128 + 0] : 0.f;
        float p5  =                  xc[128 + 1];
        float p6  =                  xc[128 + 2];
        float p7  =  x3ok          ? xc[128 + 3] : 0.f;
        float p8  =  x0ok          ? xc[256 + 0] : 0.f;
        float p9  =                  xc[256 + 1];
        float p10 =                  xc[256 + 2];
        float p11 =  x3ok          ? xc[256 + 3] : 0.f;
        float p12 = (y3ok && x0ok) ? xc[384 + 0] : 0.f;
        float p13 =  y3ok          ? xc[384 + 1] : 0.f;
        float p14 =  y3ok          ? xc[384 + 2] : 0.f;
        float p15 = (y3ok && x3ok) ? xc[384 + 3] : 0.f;
        const float* wp = wb + ic * 16;
#define FMAOC(oc) { const float* q = wp + oc * 256; \
        a##oc = fmaf(p0,  q[0],  a##oc); a##oc = fmaf(p1,  q[1],  a##oc); \
        a##oc = fmaf(p2,  q[2],  a##oc); a##oc = fmaf(p3,  q[3],  a##oc); \
        a##oc = fmaf(p4,  q[4],  a##oc); a##oc = fmaf(p5,  q[5],  a##oc); \
        a##oc = fmaf(p6,  q[6],  a##oc); a##oc = fmaf(p7,  q[7],  a##oc); \
        a##oc = fmaf(p8,  q[8],  a##oc); a##oc = fmaf(p9,  q[9],  a##oc); \
        a##oc = fmaf(p10, q[10], a##oc); a##oc = fmaf(p11, q[11], a##oc); \
        a##oc = fmaf(p12, q[12], a##oc); a##oc = fmaf(p13, q[13], a##oc); \
        a##oc = fmaf(p14, q[14], a##oc); a##oc = fmaf(p15, q[15], a##oc); }
        R8X(FMAOC)
#undef FMAOC
    }
    float* o = out + (size_t)b * (16 * 4096) + (size_t)ocb * 4096 + oy * 64 + ox;
#define STO(oc) o[oc * 4096] = fmaxf(a##oc, 0.f);
    R8X(STO)
#undef STO
}

// ---------------- residual block — oc-split halves, 2048 blocks, 8 acc/thread (NCHW) ----------------
__global__ __launch_bounds__(256) void res_k(const float* __restrict__ in, const float* __restrict__ w,
                                             const float* __restrict__ bias, float* __restrict__ out) {
    int half = blockIdx.x >> 10;
    int idx  = (blockIdx.x & 1023) * 256 + threadIdx.x;   // 64*64*64
    int ox = idx & 63;
    int oy = (idx >> 6) & 63;
    int b  = idx >> 12;
    int ocb = half * 8;
    const float* xin = in + (size_t)b * 65536;
    const float* wb  = w + (size_t)ocb * 144;
#define DECLB(i) float a##i = bias[ocb + i];
    R8X(DECLB)
#undef DECLB
    bool yt = (oy > 0), yb = (oy < 63);
    bool xl = (ox > 0), xr = (ox < 63);
    for (int ic = 0; ic < 16; ++ic) {
        const float* xb = xin + ic * 4096 + (oy - 1) * 64 + (ox - 1);
        float pa0 = (yt && xl) ? xb[0]       : 0.f;
        float pa1 =  yt        ? xb[1]       : 0.f;
        float pa2 = (yt && xr) ? xb[2]       : 0.f;
        float pb0 =  xl        ? xb[64 + 0]  : 0.f;
        float pb1 =              xb[64 + 1];
        float pb2 =  xr        ? xb[64 + 2]  : 0.f;
        float pc0 = (yb && xl) ? xb[128 + 0] : 0.f;
        float pc1 =  yb        ? xb[128 + 1] : 0.f;
        float pc2 = (yb && xr) ? xb[128 + 2] : 0.f;
        const float* wp = wb + ic * 9;
#define FMAR(oc) { const float* q = wp + oc * 144; \
        a##oc = fmaf(pa0, q[0], a##oc); a##oc = fmaf(pa1, q[1], a##oc); a##oc = fmaf(pa2, q[2], a##oc); \
        a##oc = fmaf(pb0, q[3], a##oc); a##oc = fmaf(pb1, q[4], a##oc); a##oc = fmaf(pb2, q[5], a##oc); \
        a##oc = fmaf(pc0, q[6], a##oc); a##oc = fmaf(pc1, q[7], a##oc); a##oc = fmaf(pc2, q[8], a##oc); }
        R8X(FMAR)
#undef FMAR
    }
    float* o        = out + (size_t)b * 65536 + (size_t)ocb * 4096 + oy * 64 + ox;
    const float* rr = xin + (size_t)ocb * 4096 + oy * 64 + ox;
#define RSTO(oc) o[oc * 4096] = rr[oc * 4096] + fmaxf(a##oc, 0.f);
    R8X(RSTO)
#undef RSTO
}

// ---------------- res variant for dr2: writes bf16 CHANNEL-LAST (64,64,64,16) ----------------
__global__ __launch_bounds__(256) void res_bf16_k(const float* __restrict__ in, const float* __restrict__ w,
                                                  const float* __restrict__ bias, unsigned short* __restrict__ outb) {
    int half = blockIdx.x >> 10;
    int idx  = (blockIdx.x & 1023) * 256 + threadIdx.x;   // 64*64*64
    int ox = idx & 63;
    int oy = (idx >> 6) & 63;
    int b  = idx >> 12;
    int ocb = half * 8;
    const float* xin = in + (size_t)b * 65536;
    const float* wb  = w + (size_t)ocb * 144;
#define DECLB(i) float a##i = bias[ocb + i];
    R8X(DECLB)
#undef DECLB
    bool yt = (oy > 0), yb = (oy < 63);
    bool xl = (ox > 0), xr = (ox < 63);
    for (int ic = 0; ic < 16; ++ic) {
        const float* xb = xin + ic * 4096 + (oy - 1) * 64 + (ox - 1);
        float pa0 = (yt && xl) ? xb[0]       : 0.f;
        float pa1 =  yt        ? xb[1]       : 0.f;
        float pa2 = (yt && xr) ? xb[2]       : 0.f;
        float pb0 =  xl        ? xb[64 + 0]  : 0.f;
        float pb1 =              xb[64 + 1];
        float pb2 =  xr        ? xb[64 + 2]  : 0.f;
        float pc0 = (yb && xl) ? xb[128 + 0] : 0.f;
        float pc1 =  yb        ? xb[128 + 1] : 0.f;
        float pc2 = (yb && xr) ? xb[128 + 2] : 0.f;
        const float* wp = wb + ic * 9;
#define FMAR(oc) { const float* q = wp + oc * 144; \
        a##oc = fmaf(pa0, q[0], a##oc); a##oc = fmaf(pa1, q[1], a##oc); a##oc = fmaf(pa2, q[2], a##oc); \
        a##oc = fmaf(pb0, q[3], a##oc); a##oc = fmaf(pb1, q[4], a##oc); a##oc = fmaf(pb2, q[5], a##oc); \
        a##oc = fmaf(pc0, q[6], a##oc); a##oc = fmaf(pc1, q[7], a##oc); a##oc = fmaf(pc2, q[8], a##oc); }
        R8X(FMAR)
#undef FMAR
    }
    const float* rr = xin + (size_t)ocb * 4096 + oy * 64 + ox;
    u16x8 pk;
#define PK(oc) pk[oc] = f2bf(rr[oc * 4096] + fmaxf(a##oc, 0.f));
    R8X(PK)
#undef PK
    *(u16x8*)(outb + (((size_t)b * 4096) + oy * 64 + ox) * 16 + ocb) = pk;
}

// ---------------- VQ: rows of 16 contiguous floats (raw NCHW flatten), K=64 ----------------
__global__ __launch_bounds__(256) void vq_k(const float* __restrict__ h, const float* __restrict__ cb,
                                            float* __restrict__ q, float* __restrict__ idx_out) {
    __shared__ float cbs[1024];  // 64 x 16
    __shared__ float cn[64];
    for (int i = threadIdx.x; i < 1024; i += 256) cbs[i] = cb[i];
    __syncthreads();
    if (threadIdx.x < 64) {
        float s = 0.f;
#pragma unroll
        for (int d = 0; d < 16; ++d) { float v = cbs[threadIdx.x * 16 + d]; s = fmaf(v, v, s); }
        cn[threadIdx.x] = s;
    }
    __syncthreads();
    int r = blockIdx.x * 256 + threadIdx.x;   // 262144 rows
    float f[16];
    const float4* hp = (const float4*)(h + (size_t)r * 16);
#pragma unroll
    for (int j = 0; j < 4; ++j) {
        float4 v = hp[j];
        f[j * 4 + 0] = v.x; f[j * 4 + 1] = v.y; f[j * 4 + 2] = v.z; f[j * 4 + 3] = v.w;
    }
    float best = 3.4e38f;
    int bi = 0;
    for (int k = 0; k < 64; ++k) {
        float dot = 0.f;
#pragma unroll
        for (int d = 0; d < 16; ++d) dot = fmaf(f[d], cbs[k * 16 + d], dot);
        float dist = cn[k] - 2.f * dot;   // +||f||^2 is per-row constant, argmin-invariant
        if (dist < best) { best = dist; bi = k; }
    }
    float4* qp = (float4*)(q + (size_t)r * 16);
    const float4* cp = (const float4*)(cbs + bi * 16);
#pragma unroll
    for (int j = 0; j < 4; ++j) qp[j] = cp[j];
    idx_out[r] = (float)bi;
}

// ---------------- tconv1 via MFMA: per parity class GEMM M=262144 N=16 K=64 — bf16 out ----------------
__global__ __launch_bounds__(256) void tconv1_mfma_k(const unsigned short* __restrict__ xb,
                                                     const float* __restrict__ w1, const float* __restrict__ bia,
                                                     unsigned short* __restrict__ outb) {
    int cls = blockIdx.x >> 9;           // 4 classes x 512 blocks
    int bb  = blockIdx.x & 511;
    int DY = cls >> 1, DX = cls & 1;
    int wid  = threadIdx.x >> 6;
    int lane = threadIdx.x & 63;
    int oc = lane & 15;
    int kg = lane >> 4;

    bf16x8 bfr0, bfr1;
    float accb = bia[oc];
#pragma unroll
    for (int m = 0; m < 2; ++m) {
        int tap = 2 * m + (kg >> 1);
        int ty = tap >> 1, tx = tap & 1;
        int koff = (3 - DY - 2 * ty) * 4 + (3 - DX - 2 * tx);
        int ic0 = (kg & 1) * 8;
        bf16x8 t;
#pragma unroll
        for (int j = 0; j < 8; ++j)
            t[j] = (short)f2bf(w1[(ic0 + j) * 256 + oc * 16 + koff]);
        if (m == 0) bfr0 = t; else bfr1 = t;
    }

    int Wc = bb * 4 + wid;
    for (int t = 0; t < 8; ++t) {
        int tile = Wc * 8 + t;
        int v0  = (tile & 3) * 16;
        int u   = (tile >> 2) & 63;
        int img = tile >> 8;
        const unsigned short* xi = xb + (size_t)img * 65536;
        f32x4 acc = { accb, accb, accb, accb };
#pragma unroll
        for (int m = 0; m < 2; ++m) {
            int tap = 2 * m + (kg >> 1);
            int ty = tap >> 1, tx = tap & 1;
            int jy = u + DY - 1 + ty;
            int jx = v0 + oc + DX - 1 + tx;
            bf16x8 a = { 0, 0, 0, 0, 0, 0, 0, 0 };
            if (jy >= 0 && jy < 64 && jx >= 0 && jx < 64) {
                int ic0 = (kg & 1) * 8;
                a = *(const bf16x8*)(xi + ((jy * 64 + jx) * 16 + ic0));
            }
            acc = __builtin_amdgcn_mfma_f32_16x16x32_bf16(a, (m == 0 ? bfr0 : bfr1), acc, 0, 0, 0);
        }
        int my = 2 * u + DY;
#pragma unroll
        for (int r = 0; r < 4; ++r) {
            int pxr = kg * 4 + r;
            int mx  = 2 * (v0 + pxr) + DX;
            outb[(((size_t)img * 16384) + my * 128 + mx) * 16 + oc] = f2bf(fmaxf(acc[r], 0.f));
        }
    }
}

// ---------------- tconv2: per-pixel, 4 parity classes (conv1-shape), bf16 ch-last input ----------------
template <int PY, int PX>
__device__ __forceinline__ void tconv2_body(const unsigned short* __restrict__ fb,
                                            const float* __restrict__ w2, float b2s,
                                            float* __restrict__ out, int b, int u, int v) {
    float acc = b2s;
#pragma unroll
    for (int a = 0; a < 2; ++a) {
        int jy = u + PY - 1 + a;
        if (jy < 0 || jy >= 128) continue;
#pragma unroll
        for (int c = 0; c < 2; ++c) {
            int jx = v + PX - 1 + c;
            if (jx < 0 || jx >= 128) continue;
            const int ky = 3 - PY - 2 * a;   // literal
            const int kx = 3 - PX - 2 * c;   // literal
            const unsigned short* px = fb + ((size_t)(jy * 128 + jx) << 4);
            u16x8 h0 = *(const u16x8*)px;
            u16x8 h1 = *(const u16x8*)(px + 8);
#pragma unroll
            for (int ic = 0; ic < 8; ++ic)
                acc = fmaf(bf2f(h0[ic]), w2[ic * 16 + ky * 4 + kx], acc);          // uniform -> SGPR
#pragma unroll
            for (int ic = 0; ic < 8; ++ic)
                acc = fmaf(bf2f(h1[ic]), w2[(ic + 8) * 16 + ky * 4 + kx], acc);
        }
    }
    int gy = 2 * u + PY, gx = 2 * v + PX;
    out[(size_t)b * 65536 + gy * 256 + gx] = acc;
}

__global__ __launch_bounds__(256) void tconv2_par_k(const unsigned short* __restrict__ f1b,
                                                    const float* __restrict__ w2, const float* __restrict__ b2,
                                                    float* __restrict__ out) {
    int cls = blockIdx.x >> 12;                  // 4 classes x 4096 blocks
    int idx = (blockIdx.x & 4095) * 256 + threadIdx.x;   // 64 img * 128*128
    int v = idx & 127;
    int u = (idx >> 7) & 127;
    int b = idx >> 14;
    const unsigned short* fb = f1b + (size_t)b * 262144;   // (128,128,16) ch-last bf16
    float b2s = b2[0];
    if      (cls == 0) tconv2_body<0, 0>(fb, w2, b2s, out, b, u, v);
    else if (cls == 1) tconv2_body<0, 1>(fb, w2, b2s, out, b, u, v);
    else if (cls == 2) tconv2_body<1, 0>(fb, w2, b2s, out, b, u, v);
    else               tconv2_body<1, 1>(fb, w2, b2s, out, b, u, v);
}

extern "C" void kernel_launch(void* const* d_in, const int* in_sizes, int n_in,
                              void* d_out, int out_size, void* d_ws, size_t ws_size,
                              hipStream_t stream) {
    const float* x    = (const float*)d_in[0];
    const float* c1w  = (const float*)d_in[1];
    const float* c1b  = (const float*)d_in[2];
    const float* c2w  = (const float*)d_in[3];
    const float* c2b  = (const float*)d_in[4];
    const float* er1w = (const float*)d_in[5];
    const float* er1b = (const float*)d_in[6];
    const float* er2w = (const float*)d_in[7];
    const float* er2b = (const float*)d_in[8];
    const float* cb   = (const float*)d_in[9];
    const float* dr1w = (const float*)d_in[10];
    const float* dr1b = (const float*)d_in[11];
    const float* dr2w = (const float*)d_in[12];
    const float* dr2b = (const float*)d_in[13];
    const float* t1w  = (const float*)d_in[14];
    const float* t1b  = (const float*)d_in[15];
    const float* t2w  = (const float*)d_in[16];
    const float* t2b  = (const float*)d_in[17];

    float* f1 = (float*)d_ws;                                // 64 MiB: enc fp32 NCHW / dec bf16 ch-last
    float* f2 = (float*)((char*)d_ws + 67108864);            // (64,16,64,64)
    float* f3 = (float*)((char*)d_ws + 67108864 + 16777216); // (64,16,64,64) / bf16 ch-last (8.4 MiB)

    float* out     = (float*)d_out;                          // decoded: 4,194,304 f32
    float* idx_out = out + 4194304;                          // indices: 262,144 f32

    conv1_k      <<<4096,  256, 0, stream>>>(x, c1w, c1b, f1);
    conv2_k      <<<2048,  256, 0, stream>>>(f1, c2w, c2b, f2);
    res_k        <<<2048,  256, 0, stream>>>(f2, er1w, er1b, f3);  // er1
    res_k        <<<2048,  256, 0, stream>>>(f3, er2w, er2b, f2);  // er2
    vq_k         <<<1024,  256, 0, stream>>>(f2, cb, f3, idx_out); // quantized -> f3
    res_k        <<<2048,  256, 0, stream>>>(f3, dr1w, dr1b, f2);  // dr1
    res_bf16_k   <<<2048,  256, 0, stream>>>(f2, dr2w, dr2b, (unsigned short*)f3);  // dr2 -> bf16 ch-last
    tconv1_mfma_k<<<2048,  256, 0, stream>>>((const unsigned short*)f3, t1w, t1b, (unsigned short*)f1);
    tconv2_par_k <<<16384, 256, 0, stream>>>((const unsigned short*)f1, t2w, t2b, out);
}

// Round 20
// 258.082 us; speedup vs baseline: 2.9365x; 1.0878x over previous
//
#include <hip/hip_runtime.h>
#include <hip/hip_bf16.h>

// VQ-VAE forward, B=64, F=16.  ALL I/O float32 (d_out = float*: decoded 4194304 f32, indices 262144 f32).
// ws: f1 64 MiB (enc: hi/lo bf16 ch-last planes 32+32 MiB; dec: bf16 ch-last) | f2 16 MiB | f3 16 MiB.
// R20: conv2 -> split-bf16 MFMA. conv1 emits hi/lo bf16 ch-last; conv2 = 3 error-compensated MFMA
//      chains (ah*bh + ah*bl + al*bh), K=256, weights pre-split into LDS [oc][264] (2-way only).
//      Split error ~2^-18 (~4e-6 rel) ~ fp32-reorder noise that already passes -> indices expected exact.
// Pre-commit: Output1 fails -> revert conv2 to R19 scalar; Output0-only fails -> frag-layout bug.
// Lessons: uniform weights -> SGPR (R10); matrix pipe beats scalar-conv wall (R17); small-state or
//      bust (R11-R18); never full-unroll wide vector loads (R7,R18); stage once barrier once (R8).

#define R16X(M) M(0) M(1) M(2) M(3) M(4) M(5) M(6) M(7) M(8) M(9) M(10) M(11) M(12) M(13) M(14) M(15)
#define R8X(M)  M(0) M(1) M(2) M(3) M(4) M(5) M(6) M(7)

typedef __attribute__((ext_vector_type(8))) short          bf16x8;
typedef __attribute__((ext_vector_type(8))) unsigned short u16x8;
typedef __attribute__((ext_vector_type(4))) float          f32x4;

__device__ __forceinline__ unsigned short f2bf(float f) {   // RNE fp32 -> bf16 bits
    unsigned u; __builtin_memcpy(&u, &f, 4);
    unsigned r = u + 0x7FFFu + ((u >> 16) & 1u);
    return (unsigned short)(r >> 16);
}
__device__ __forceinline__ float bf2f(unsigned short h) {
    unsigned u = ((unsigned)h) << 16;
    float f; __builtin_memcpy(&f, &u, 4);
    return f;
}

// ---------------- conv1: 1->16, 256->128 — writes hi/lo bf16 CHANNEL-LAST planes ----------------
__global__ __launch_bounds__(256) void conv1_k(const float* __restrict__ x, const float* __restrict__ w,
                                               const float* __restrict__ bias,
                                               unsigned short* __restrict__ oh, unsigned short* __restrict__ ol) {
    int idx = blockIdx.x * 256 + threadIdx.x;   // 64*128*128
    int ox = idx & 127;
    int oy = (idx >> 7) & 127;
    int b  = idx >> 14;
    const float* xin = x + (size_t)b * 65536;
    float pv[16];
#pragma unroll
    for (int ky = 0; ky < 4; ++ky) {
        int iy = 2 * oy - 1 + ky;
#pragma unroll
        for (int kx = 0; kx < 4; ++kx) {
            int ix = 2 * ox - 1 + kx;
            pv[ky * 4 + kx] = (iy >= 0 && iy < 256 && ix >= 0 && ix < 256)
                                  ? xin[iy * 256 + ix] : 0.f;
        }
    }
    u16x8 h0, h1, l0, l1;
#pragma unroll
    for (int oc = 0; oc < 16; ++oc) {
        float acc = bias[oc];
#pragma unroll
        for (int k = 0; k < 16; ++k) acc = fmaf(pv[k], w[oc * 16 + k], acc);
        float r = fmaxf(acc, 0.f);
        unsigned short hb = f2bf(r);
        unsigned short lb = f2bf(r - bf2f(hb));
        if (oc < 8) { h0[oc] = hb; l0[oc] = lb; }
        else        { h1[oc - 8] = hb; l1[oc - 8] = lb; }
    }
    u16x8* po = (u16x8*)(oh + (size_t)idx * 16);
    po[0] = h0; po[1] = h1;
    u16x8* pl = (u16x8*)(ol + (size_t)idx * 16);
    pl[0] = l0; pl[1] = l1;
}

// ---------------- conv2 via split-bf16 MFMA: GEMM M=262144 N=16 K=256, 3 chains ----------------
// A[px][k] (k=tap*16+ic, tap=ky*4+kx) from hi/lo ch-last planes; B from LDS [oc][264] (pre-split).
// Frag mapping identical to R17-verified tconv1_mfma: A row=lane&15, k=(lane>>4)*8+j; C col=lane&15.
__global__ __launch_bounds__(256) void conv2_mfma_k(const unsigned short* __restrict__ fh,
                                                    const unsigned short* __restrict__ fl,
                                                    const float* __restrict__ w, const float* __restrict__ bias,
                                                    float* __restrict__ out) {
    __shared__ unsigned short wsh[16 * 264];   // [oc][k pad 264] hi
    __shared__ unsigned short wsl[16 * 264];   // lo
    for (int i = threadIdx.x; i < 4096; i += 256) {
        int oc = i >> 8, k = i & 255;
        int ic = k & 15, tap = k >> 4;
        float f = w[oc * 256 + ic * 16 + tap];
        unsigned short hb = f2bf(f);
        wsh[oc * 264 + k] = hb;
        wsl[oc * 264 + k] = f2bf(f - bf2f(hb));
    }
    __syncthreads();

    int wid  = threadIdx.x >> 6;
    int lane = threadIdx.x & 63;
    int col = lane & 15;                 // A row (px) / B col (oc) / C col (oc)
    int kg  = lane >> 4;
    int ic0 = (kg & 1) * 8;
    float accb = bias[col];
    int gw = blockIdx.x * 4 + wid;       // 0..8191

    for (int t = 0; t < 2; ++t) {
        int tile = gw * 2 + t;           // 0..16383 : img(64) x y(64) x 4 col-segments
        int v0  = (tile & 3) * 16;
        int y   = (tile >> 2) & 63;
        int img = tile >> 8;
        const unsigned short* bh = fh + (size_t)img * 262144;   // (128,128,16)
        const unsigned short* bl = fl + (size_t)img * 262144;
        f32x4 acc = { accb, accb, accb, accb };
#pragma unroll
        for (int m = 0; m < 8; ++m) {
            int tap = 2 * m + (kg >> 1);
            int ty = tap >> 2, tx = tap & 3;
            int jy = 2 * y - 1 + ty;
            int jx = 2 * (v0 + col) - 1 + tx;
            bf16x8 ah = { 0, 0, 0, 0, 0, 0, 0, 0 };
            bf16x8 al = { 0, 0, 0, 0, 0, 0, 0, 0 };
            if (jy >= 0 && jy < 128 && jx >= 0 && jx < 128) {
                size_t off = ((size_t)(jy * 128 + jx)) * 16 + ic0;
                ah = *(const bf16x8*)(bh + off);
                al = *(const bf16x8*)(bl + off);
            }
            bf16x8 wh = *(const bf16x8*)&wsh[col * 264 + m * 32 + kg * 8];
            bf16x8 wl = *(const bf16x8*)&wsl[col * 264 + m * 32 + kg * 8];
            acc = __builtin_amdgcn_mfma_f32_16x16x32_bf16(ah, wh, acc, 0, 0, 0);
            acc = __builtin_amdgcn_mfma_f32_16x16x32_bf16(al, wh, acc, 0, 0, 0);
            acc = __builtin_amdgcn_mfma_f32_16x16x32_bf16(ah, wl, acc, 0, 0, 0);
        }
        float* o = out + (size_t)img * 65536 + col * 4096 + y * 64 + v0;   // NCHW, oc=col
#pragma unroll
        for (int r = 0; r < 4; ++r) {
            int px = kg * 4 + r;
            o[px] = fmaxf(acc[r], 0.f);
        }
    }
}

// ---------------- residual block — oc-split halves, 2048 blocks, 8 acc/thread (NCHW) ----------------
__global__ __launch_bounds__(256) void res_k(const float* __restrict__ in, const float* __restrict__ w,
                                             const float* __restrict__ bias, float* __restrict__ out) {
    int half = blockIdx.x >> 10;
    int idx  = (blockIdx.x & 1023) * 256 + threadIdx.x;   // 64*64*64
    int ox = idx & 63;
    int oy = (idx >> 6) & 63;
    int b  = idx >> 12;
    int ocb = half * 8;
    const float* xin = in + (size_t)b * 65536;
    const float* wb  = w + (size_t)ocb * 144;
#define DECLB(i) float a##i = bias[ocb + i];
    R8X(DECLB)
#undef DECLB
    bool yt = (oy > 0), yb = (oy < 63);
    bool xl = (ox > 0), xr = (ox < 63);
    for (int ic = 0; ic < 16; ++ic) {
        const float* xb = xin + ic * 4096 + (oy - 1) * 64 + (ox - 1);
        float pa0 = (yt && xl) ? xb[0]       : 0.f;
        float pa1 =  yt        ? xb[1]       : 0.f;
        float pa2 = (yt && xr) ? xb[2]       : 0.f;
        float pb0 =  xl        ? xb[64 + 0]  : 0.f;
        float pb1 =              xb[64 + 1];
        float pb2 =  xr        ? xb[64 + 2]  : 0.f;
        float pc0 = (yb && xl) ? xb[128 + 0] : 0.f;
        float pc1 =  yb        ? xb[128 + 1] : 0.f;
        float pc2 = (yb && xr) ? xb[128 + 2] : 0.f;
        const float* wp = wb + ic * 9;
#define FMAR(oc) { const float* q = wp + oc * 144; \
        a##oc = fmaf(pa0, q[0], a##oc); a##oc = fmaf(pa1, q[1], a##oc); a##oc = fmaf(pa2, q[2], a##oc); \
        a##oc = fmaf(pb0, q[3], a##oc); a##oc = fmaf(pb1, q[4], a##oc); a##oc = fmaf(pb2, q[5], a##oc); \
        a##oc = fmaf(pc0, q[6], a##oc); a##oc = fmaf(pc1, q[7], a##oc); a##oc = fmaf(pc2, q[8], a##oc); }
        R8X(FMAR)
#undef FMAR
    }
    float* o        = out + (size_t)b * 65536 + (size_t)ocb * 4096 + oy * 64 + ox;
    const float* rr = xin + (size_t)ocb * 4096 + oy * 64 + ox;
#define RSTO(oc) o[oc * 4096] = rr[oc * 4096] + fmaxf(a##oc, 0.f);
    R8X(RSTO)
#undef RSTO
}

// ---------------- res variant for dr2: writes bf16 CHANNEL-LAST (64,64,64,16) ----------------
__global__ __launch_bounds__(256) void res_bf16_k(const float* __restrict__ in, const float* __restrict__ w,
                                                  const float* __restrict__ bias, unsigned short* __restrict__ outb) {
    int half = blockIdx.x >> 10;
    int idx  = (blockIdx.x & 1023) * 256 + threadIdx.x;   // 64*64*64
    int ox = idx & 63;
    int oy = (idx >> 6) & 63;
    int b  = idx >> 12;
    int ocb = half * 8;
    const float* xin = in + (size_t)b * 65536;
    const float* wb  = w + (size_t)ocb * 144;
#define DECLB(i) float a##i = bias[ocb + i];
    R8X(DECLB)
#undef DECLB
    bool yt = (oy > 0), yb = (oy < 63);
    bool xl = (ox > 0), xr = (ox < 63);
    for (int ic = 0; ic < 16; ++ic) {
        const float* xb = xin + ic * 4096 + (oy - 1) * 64 + (ox - 1);
        float pa0 = (yt && xl) ? xb[0]       : 0.f;
        float pa1 =  yt        ? xb[1]       : 0.f;
        float pa2 = (yt && xr) ? xb[2]       : 0.f;
        float pb0 =  xl        ? xb[64 + 0]  : 0.f;
        float pb1 =              xb[64 + 1];
        float pb2 =  xr        ? xb[64 + 2]  : 0.f;
        float pc0 = (yb && xl) ? xb[128 + 0] : 0.f;
        float pc1 =  yb        ? xb[128 + 1] : 0.f;
        float pc2 = (yb && xr) ? xb[128 + 2] : 0.f;
        const float* wp = wb + ic * 9;
#define FMAR(oc) { const float* q = wp + oc * 144; \
        a##oc = fmaf(pa0, q[0], a##oc); a##oc = fmaf(pa1, q[1], a##oc); a##oc = fmaf(pa2, q[2], a##oc); \
        a##oc = fmaf(pb0, q[3], a##oc); a##oc = fmaf(pb1, q[4], a##oc); a##oc = fmaf(pb2, q[5], a##oc); \
        a##oc = fmaf(pc0, q[6], a##oc); a##oc = fmaf(pc1, q[7], a##oc); a##oc = fmaf(pc2, q[8], a##oc); }
        R8X(FMAR)
#undef FMAR
    }
    const float* rr = xin + (size_t)ocb * 4096 + oy * 64 + ox;
    u16x8 pk;
#define PK(oc) pk[oc] = f2bf(rr[oc * 4096] + fmaxf(a##oc, 0.f));
    R8X(PK)
#undef PK
    *(u16x8*)(outb + (((size_t)b * 4096) + oy * 64 + ox) * 16 + ocb) = pk;
}

// ---------------- VQ: rows of 16 contiguous floats (raw NCHW flatten), K=64 ----------------
__global__ __launch_bounds__(256) void vq_k(const float* __restrict__ h, const float* __restrict__ cb,
                                            float* __restrict__ q, float* __restrict__ idx_out) {
    __shared__ float cbs[1024];  // 64 x 16
    __shared__ float cn[64];
    for (int i = threadIdx.x; i < 1024; i += 256) cbs[i] = cb[i];
    __syncthreads();
    if (threadIdx.x < 64) {
        float s = 0.f;
#pragma unroll
        for (int d = 0; d < 16; ++d) { float v = cbs[threadIdx.x * 16 + d]; s = fmaf(v, v, s); }
        cn[threadIdx.x] = s;
    }
    __syncthreads();
    int r = blockIdx.x * 256 + threadIdx.x;   // 262144 rows
    float f[16];
    const float4* hp = (const float4*)(h + (size_t)r * 16);
#pragma unroll
    for (int j = 0; j < 4; ++j) {
        float4 v = hp[j];
        f[j * 4 + 0] = v.x; f[j * 4 + 1] = v.y; f[j * 4 + 2] = v.z; f[j * 4 + 3] = v.w;
    }
    float best = 3.4e38f;
    int bi = 0;
    for (int k = 0; k < 64; ++k) {
        float dot = 0.f;
#pragma unroll
        for (int d = 0; d < 16; ++d) dot = fmaf(f[d], cbs[k * 16 + d], dot);
        float dist = cn[k] - 2.f * dot;   // +||f||^2 is per-row constant, argmin-invariant
        if (dist < best) { best = dist; bi = k; }
    }
    float4* qp = (float4*)(q + (size_t)r * 16);
    const float4* cp = (const float4*)(cbs + bi * 16);
#pragma unroll
    for (int j = 0; j < 4; ++j) qp[j] = cp[j];
    idx_out[r] = (float)bi;
}

// ---------------- tconv1 via MFMA: per parity class GEMM M=262144 N=16 K=64 — bf16 out ----------------
__global__ __launch_bounds__(256) void tconv1_mfma_k(const unsigned short* __restrict__ xb,
                                                     const float* __restrict__ w1, const float* __restrict__ bia,
                                                     unsigned short* __restrict__ outb) {
    int cls = blockIdx.x >> 9;           // 4 classes x 512 blocks
    int bb  = blockIdx.x & 511;
    int DY = cls >> 1, DX = cls & 1;
    int wid  = threadIdx.x >> 6;
    int lane = threadIdx.x & 63;
    int oc = lane & 15;
    int kg = lane >> 4;

    bf16x8 bfr0, bfr1;
    float accb = bia[oc];
#pragma unroll
    for (int m = 0; m < 2; ++m) {
        int tap = 2 * m + (kg >> 1);
        int ty = tap >> 1, tx = tap & 1;
        int koff = (3 - DY - 2 * ty) * 4 + (3 - DX - 2 * tx);
        int ic0 = (kg & 1) * 8;
        bf16x8 t;
#pragma unroll
        for (int j = 0; j < 8; ++j)
            t[j] = (short)f2bf(w1[(ic0 + j) * 256 + oc * 16 + koff]);
        if (m == 0) bfr0 = t; else bfr1 = t;
    }

    int Wc = bb * 4 + wid;
    for (int t = 0; t < 8; ++t) {
        int tile = Wc * 8 + t;
        int v0  = (tile & 3) * 16;
        int u   = (tile >> 2) & 63;
        int img = tile >> 8;
        const unsigned short* xi = xb + (size_t)img * 65536;
        f32x4 acc = { accb, accb, accb, accb };
#pragma unroll
        for (int m = 0; m < 2; ++m) {
            int tap = 2 * m + (kg >> 1);
            int ty = tap >> 1, tx = tap & 1;
            int jy = u + DY - 1 + ty;
            int jx = v0 + oc + DX - 1 + tx;
            bf16x8 a = { 0, 0, 0, 0, 0, 0, 0, 0 };
            if (jy >= 0 && jy < 64 && jx >= 0 && jx < 64) {
                int ic0 = (kg & 1) * 8;
                a = *(const bf16x8*)(xi + ((jy * 64 + jx) * 16 + ic0));
            }
            acc = __builtin_amdgcn_mfma_f32_16x16x32_bf16(a, (m == 0 ? bfr0 : bfr1), acc, 0, 0, 0);
        }
        int my = 2 * u + DY;
#pragma unroll
        for (int r = 0; r < 4; ++r) {
            int pxr = kg * 4 + r;
            int mx  = 2 * (v0 + pxr) + DX;
            outb[(((size_t)img * 16384) + my * 128 + mx) * 16 + oc] = f2bf(fmaxf(acc[r], 0.f));
        }
    }
}

// ---------------- tconv2: per-pixel, 4 parity classes (conv1-shape), bf16 ch-last input ----------------
template <int PY, int PX>
__device__ __forceinline__ void tconv2_body(const unsigned short* __restrict__ fb,
                                            const float* __restrict__ w2, float b2s,
                                            float* __restrict__ out, int b, int u, int v) {
    float acc = b2s;
#pragma unroll
    for (int a = 0; a < 2; ++a) {
        int jy = u + PY - 1 + a;
        if (jy < 0 || jy >= 128) continue;
#pragma unroll
        for (int c = 0; c < 2; ++c) {
            int jx = v + PX - 1 + c;
            if (jx < 0 || jx >= 128) continue;
            const int ky = 3 - PY - 2 * a;   // literal
            const int kx = 3 - PX - 2 * c;   // literal
            const unsigned short* px = fb + ((size_t)(jy * 128 + jx) << 4);
            u16x8 h0 = *(const u16x8*)px;
            u16x8 h1 = *(const u16x8*)(px + 8);
#pragma unroll
            for (int ic = 0; ic < 8; ++ic)
                acc = fmaf(bf2f(h0[ic]), w2[ic * 16 + ky * 4 + kx], acc);          // uniform -> SGPR
#pragma unroll
            for (int ic = 0; ic < 8; ++ic)
                acc = fmaf(bf2f(h1[ic]), w2[(ic + 8) * 16 + ky * 4 + kx], acc);
        }
    }
    int gy = 2 * u + PY, gx = 2 * v + PX;
    out[(size_t)b * 65536 + gy * 256 + gx] = acc;
}

__global__ __launch_bounds__(256) void tconv2_par_k(const unsigned short* __restrict__ f1b,
                                                    const float* __restrict__ w2, const float* __restrict__ b2,
                                                    float* __restrict__ out) {
    int cls = blockIdx.x >> 12;                  // 4 classes x 4096 blocks
    int idx = (blockIdx.x & 4095) * 256 + threadIdx.x;   // 64 img * 128*128
    int v = idx & 127;
    int u = (idx >> 7) & 127;
    int b = idx >> 14;
    const unsigned short* fb = f1b + (size_t)b * 262144;   // (128,128,16) ch-last bf16
    float b2s = b2[0];
    if      (cls == 0) tconv2_body<0, 0>(fb, w2, b2s, out, b, u, v);
    else if (cls == 1) tconv2_body<0, 1>(fb, w2, b2s, out, b, u, v);
    else if (cls == 2) tconv2_body<1, 0>(fb, w2, b2s, out, b, u, v);
    else               tconv2_body<1, 1>(fb, w2, b2s, out, b, u, v);
}

extern "C" void kernel_launch(void* const* d_in, const int* in_sizes, int n_in,
                              void* d_out, int out_size, void* d_ws, size_t ws_size,
                              hipStream_t stream) {
    const float* x    = (const float*)d_in[0];
    const float* c1w  = (const float*)d_in[1];
    const float* c1b  = (const float*)d_in[2];
    const float* c2w  = (const float*)d_in[3];
    const float* c2b  = (const float*)d_in[4];
    const float* er1w = (const float*)d_in[5];
    const float* er1b = (const float*)d_in[6];
    const float* er2w = (const float*)d_in[7];
    const float* er2b = (const float*)d_in[8];
    const float* cb   = (const float*)d_in[9];
    const float* dr1w = (const float*)d_in[10];
    const float* dr1b = (const float*)d_in[11];
    const float* dr2w = (const float*)d_in[12];
    const float* dr2b = (const float*)d_in[13];
    const float* t1w  = (const float*)d_in[14];
    const float* t1b  = (const float*)d_in[15];
    const float* t2w  = (const float*)d_in[16];
    const float* t2b  = (const float*)d_in[17];

    unsigned short* f1h = (unsigned short*)d_ws;             // 32 MiB: conv1 hi (64,128,128,16) bf16
    unsigned short* f1l = f1h + 16777216;                    // 32 MiB: conv1 lo
    float* f2 = (float*)((char*)d_ws + 67108864);            // (64,16,64,64) fp32
    float* f3 = (float*)((char*)d_ws + 67108864 + 16777216); // (64,16,64,64) fp32 / bf16 ch-last

    float* out     = (float*)d_out;                          // decoded: 4,194,304 f32
    float* idx_out = out + 4194304;                          // indices: 262,144 f32

    conv1_k      <<<4096,  256, 0, stream>>>(x, c1w, c1b, f1h, f1l);
    conv2_mfma_k <<<2048,  256, 0, stream>>>(f1h, f1l, c2w, c2b, f2);
    res_k        <<<2048,  256, 0, stream>>>(f2, er1w, er1b, f3);  // er1
    res_k        <<<2048,  256, 0, stream>>>(f3, er2w, er2b, f2);  // er2
    vq_k         <<<1024,  256, 0, stream>>>(f2, cb, f3, idx_out); // quantized -> f3
    res_k        <<<2048,  256, 0, stream>>>(f3, dr1w, dr1b, f2);  // dr1
    res_bf16_k   <<<2048,  256, 0, stream>>>(f2, dr2w, dr2b, (unsigned short*)f3);  // dr2 -> bf16 ch-last
    tconv1_mfma_k<<<2048,  256, 0, stream>>>((const unsigned short*)f3, t1w, t1b, (unsigned short*)f1h);
    tconv2_par_k <<<16384, 256, 0, stream>>>((const unsigned short*)f1h, t2w, t2b, out);
}